// Round 4
// baseline (84.654 us; speedup 1.0000x reference)
//
#include <hip/hip_runtime.h>

// PiecewisePolynomial: out[b,o] = sum_i sum_j L_j(x_in(b,i)) * w[o, i, 3*seg(b,i)+j]
// B=512, IN_F=256, OUT_F=256, SEGMENTS=16, N=4 (nodes -1,-0.5,0.5,1)
//
// R10: latency-exposure fixes on the R9 structure.
// (a) pp_partial: split-drain staging. VMEM issue order pinned to
//     [x-loads][stage i0..7][stage i8..15]; after basis VALU,
//     s_waitcnt vmcnt(4)+s_barrier lets compute on i0..7 start while the
//     second half is still in flight (in-order VMEM retirement => vmcnt(4)
//     == first 4 stage instrs per wave complete). Then vmcnt(0)+barrier,
//     compute i8..15. Halves the exposed stage drain of the old single
//     __syncthreads (which waits vmcnt(0)).
// (b) pp_expand: c-loop -> blockIdx.y. 512 blocks x 25KB LDS = ~6
//     blocks/CU resident; cross-block overlap hides the 4-phase chain.
// (c) pp_reduce: 256 blocks x 128 threads -> all CUs engaged.

typedef _Float16 h2 __attribute__((ext_vector_type(2)));

#define INF     256
#define OUTF    256
#define WSTRIDE 49
#define OSTRIDE (INF * WSTRIDE)       // 12544
#define NSPLIT  16
#define IPB     16
#define WE_UINTS (256 * 128 * 64)     // 2,097,152 uints = 8.39 MB

#define GLOAD16(gptr, lptr)                                                         \
  __builtin_amdgcn_global_load_lds(                                                 \
      (const __attribute__((address_space(1))) unsigned int*)(gptr),                \
      (__attribute__((address_space(3))) unsigned int*)(lptr), 16, 0, 0)

// ---- expand: block = (o-pair, 64-i chunk). Stage contiguous w rows into LDS
// (coalesced 16B), convert, write we[i][op][s] 16B units in contiguous 256B
// runs. we[i][op][s] = {e0 pair0, e0 pair1, e1 pair0, e1 pair1},
// pair0 = f16x2(w[3s],w[3s+1]), pair1 = f16x2(w[3s+2],w[3s+3]).
__global__ __launch_bounds__(256)
void pp_expand(const float* __restrict__ w, unsigned int* __restrict__ we) {
    __shared__ float lds_w[2][3136];      // 2 o x 64 i x 49 f32 = 25 KB

    const int tid   = threadIdx.x;
    const int op    = blockIdx.x >> 1;    // 0..127
    const int ihalf = blockIdx.x & 1;     // 0..1
    const int c     = blockIdx.y;         // 0..1
    const int o0    = op * 2;
    const int i_c   = ihalf * 128 + c * 64;   // i chunk base (64 i's)

    // stage: 2 x 784 float4, coalesced, 16B-aligned (64*49 floats = 12544B)
    #pragma unroll
    for (int oe = 0; oe < 2; ++oe) {
        const float* src = w + (size_t)(o0 + oe) * OSTRIDE + (size_t)i_c * WSTRIDE;
        #pragma unroll
        for (int it = 0; it < 4; ++it) {
            int u = it * 256 + tid;           // float4 index 0..1023
            if (u < 784)
                GLOAD16(src + u * 4, &lds_w[oe][u * 4]);
        }
    }
    __syncthreads();   // drains vmcnt -> LDS valid

    // convert: 64 i x 16 s items; lanes walk s fastest -> 16B stores form
    // contiguous 256B runs per i.
    #pragma unroll
    for (int r = 0; r < 4; ++r) {
        int item = r * 256 + tid;             // 0..1023
        int il = item >> 4, s = item & 15;
        const float* t0 = &lds_w[0][il * 49 + 3 * s];
        const float* t1 = &lds_w[1][il * 49 + 3 * s];
        uint4 v;
        v.x = __builtin_bit_cast(unsigned int,
                  __builtin_amdgcn_cvt_pkrtz(t0[0], t0[1]));
        v.y = __builtin_bit_cast(unsigned int,
                  __builtin_amdgcn_cvt_pkrtz(t0[2], t0[3]));
        v.z = __builtin_bit_cast(unsigned int,
                  __builtin_amdgcn_cvt_pkrtz(t1[0], t1[1]));
        v.w = __builtin_bit_cast(unsigned int,
                  __builtin_amdgcn_cvt_pkrtz(t1[2], t1[3]));
        *(uint4*)(we + (((size_t)(i_c + il) * 128 + op) * 16 + s) * 4) = v;
    }
}

// ---- partial: 512 threads, 8 waves = 4 o-subranges x 2 b-halves.
// One 64KB staged slice serves 128 batch rows. Split-drain staging:
// compute on i0..7 overlaps the in-flight stage of i8..15.
__global__ __launch_bounds__(512, 4)
void pp_partial(const float* __restrict__ x, const unsigned int* __restrict__ we,
                float* __restrict__ part) {
    __shared__ unsigned int smem[16384];  // 16i x 16op x 16s x 16B = 64 KB

    const int tid  = threadIdx.x;
    const int wave = tid >> 6, lane = tid & 63;
    const int osub = wave & 3;                 // o-subrange within the 32-o tile
    const int bsub = wave >> 2;                // b-half within the 128-b tile
    const int isplit  = blockIdx.x;            // 0..15
    const int i_base  = isplit * IPB;          // *16
    const int op_base = blockIdx.y * 16;       // o_base = blockIdx.y*32
    const int o_base  = blockIdx.y * 32;
    const int b_base  = blockIdx.z * 128;
    const int b = b_base + bsub * 64 + lane;   // this lane's batch row

    // ---- VMEM issue order: x-loads FIRST (so their waitcnt doesn't drain
    // the stage), then stage A (i0..7), then stage B (i8..15). ----
    const float4* xp = (const float4*)(x + (size_t)b * INF + i_base);
    float4 x0 = xp[0], x1 = xp[1], x2 = xp[2], x3 = xp[3];
    __builtin_amdgcn_sched_barrier(0);

    #pragma unroll
    for (int it = 0; it < 4; ++it) {           // stage A: units 0..2047 (i0..7)
        int u = it * 512 + tid;
        int iloc = u >> 8, opl = (u >> 4) & 15, s = u & 15;
        const unsigned int* gp =
            we + (((size_t)(i_base + iloc) * 128 + op_base + opl) * 16 + s) * 4;
        GLOAD16(gp, &smem[u * 4]);
    }
    __builtin_amdgcn_sched_barrier(0);
    #pragma unroll
    for (int it = 4; it < 8; ++it) {           // stage B: units 2048..4095 (i8..15)
        int u = it * 512 + tid;
        int iloc = u >> 8, opl = (u >> 4) & 15, s = u & 15;
        const unsigned int* gp =
            we + (((size_t)(i_base + iloc) * 128 + op_base + opl) * 16 + s) * 4;
        GLOAD16(gp, &smem[u * 4]);
    }
    __builtin_amdgcn_sched_barrier(0);

    // ---- per-lane basis + segment (x uses wait only on the x-loads: they are
    // the OLDEST 4 VMEM ops, so the compiler's waitcnt leaves the stage in
    // flight) ----
    int sseg[IPB]; h2 cA[IPB], cB[IPB];
    {
        float xs[16] = {x0.x, x0.y, x0.z, x0.w, x1.x, x1.y, x1.z, x1.w,
                        x2.x, x2.y, x2.z, x2.w, x3.x, x3.y, x3.z, x3.w};
        #pragma unroll
        for (int i = 0; i < IPB; ++i) {
            float xx = xs[i];
            int id = (int)((xx + 1.0f) * 8.0f);
            id = id < 0 ? 0 : (id > 15 ? 15 : id);
            float u = (xx - ((float)id * 0.125f - 1.0f)) * 16.0f - 1.0f;
            float a = u + 1.0f, b2 = u + 0.5f, cc = u - 0.5f, d = u - 1.0f;
            float c0 = b2 * cc * d  * (-2.0f / 3.0f);
            float c1 = a  * cc * d  * ( 4.0f / 3.0f);
            float c2 = a  * b2 * d  * (-4.0f / 3.0f);
            float c3 = a  * b2 * cc * ( 2.0f / 3.0f);
            h2 pA; pA[0] = (_Float16)c0; pA[1] = (_Float16)c1;
            h2 pB; pB[0] = (_Float16)c2; pB[1] = (_Float16)c3;
            cA[i] = pA; cB[i] = pB; sseg[i] = id;
        }
    }

    float acc[8];
    #pragma unroll
    for (int q = 0; q < 8; ++q) acc[q] = 0.0f;

    // ---- barrier 1: stage A drained (vmcnt(4): 4 stage-B instrs may remain) ----
    asm volatile("s_waitcnt vmcnt(4)" ::: "memory");
    __builtin_amdgcn_s_barrier();
    __builtin_amdgcn_sched_barrier(0);

    // ---- compute i = 0..7 (stage B still landing underneath) ----
    #pragma unroll
    for (int i = 0; i < 8; ++i) {
        const unsigned int* p = &smem[(i * 16 + osub * 4) * 64 + sseg[i] * 4];
        #pragma unroll
        for (int pq = 0; pq < 4; ++pq) {
            uint4 v = *(const uint4*)(p + pq * 64);
            acc[2*pq]   = __builtin_amdgcn_fdot2(__builtin_bit_cast(h2, v.x), cA[i],
                                                 acc[2*pq],   false);
            acc[2*pq]   = __builtin_amdgcn_fdot2(__builtin_bit_cast(h2, v.y), cB[i],
                                                 acc[2*pq],   false);
            acc[2*pq+1] = __builtin_amdgcn_fdot2(__builtin_bit_cast(h2, v.z), cA[i],
                                                 acc[2*pq+1], false);
            acc[2*pq+1] = __builtin_amdgcn_fdot2(__builtin_bit_cast(h2, v.w), cB[i],
                                                 acc[2*pq+1], false);
        }
    }
    __builtin_amdgcn_sched_barrier(0);

    // ---- barrier 2: stage B drained ----
    asm volatile("s_waitcnt vmcnt(0)" ::: "memory");
    __builtin_amdgcn_s_barrier();
    __builtin_amdgcn_sched_barrier(0);

    // ---- compute i = 8..15 ----
    #pragma unroll
    for (int i = 8; i < 16; ++i) {
        const unsigned int* p = &smem[(i * 16 + osub * 4) * 64 + sseg[i] * 4];
        #pragma unroll
        for (int pq = 0; pq < 4; ++pq) {
            uint4 v = *(const uint4*)(p + pq * 64);
            acc[2*pq]   = __builtin_amdgcn_fdot2(__builtin_bit_cast(h2, v.x), cA[i],
                                                 acc[2*pq],   false);
            acc[2*pq]   = __builtin_amdgcn_fdot2(__builtin_bit_cast(h2, v.y), cB[i],
                                                 acc[2*pq],   false);
            acc[2*pq+1] = __builtin_amdgcn_fdot2(__builtin_bit_cast(h2, v.z), cA[i],
                                                 acc[2*pq+1], false);
            acc[2*pq+1] = __builtin_amdgcn_fdot2(__builtin_bit_cast(h2, v.w), cB[i],
                                                 acc[2*pq+1], false);
        }
    }

    // ---- LDS transpose (lane=b -> lane=o) + coalesced float4 partial stores ----
    __syncthreads();                      // weights no longer needed
    float* smf = (float*)smem;            // [128 b][33] fp32 = 16.9 KB
    const int b_l0 = bsub * 64 + lane;
    #pragma unroll
    for (int q = 0; q < 8; ++q)
        smf[b_l0 * 33 + osub * 8 + q] = acc[q];
    __syncthreads();

    const int qo = tid & 7;               // o-quad 0..7 (4 floats each)
    const int g  = tid >> 3;              // 0..63
    #pragma unroll
    for (int r = 0; r < 2; ++r) {
        int b_l = g + 64 * r;
        float4 v;
        v.x = smf[b_l * 33 + qo * 4 + 0];
        v.y = smf[b_l * 33 + qo * 4 + 1];
        v.z = smf[b_l * 33 + qo * 4 + 2];
        v.w = smf[b_l * 33 + qo * 4 + 3];
        *(float4*)(part + (size_t)isplit * (512 * 256)
                        + (size_t)(b_base + b_l) * 256 + o_base + qo * 4) = v;
    }
}

__global__ __launch_bounds__(128)
void pp_reduce(const float* __restrict__ part, float* __restrict__ out) {
    const size_t off4 = (size_t)blockIdx.x * 128 + threadIdx.x;  // float4 index
    const float4* p4 = (const float4*)part;
    float4 s = make_float4(0.f, 0.f, 0.f, 0.f);
    #pragma unroll
    for (int k = 0; k < NSPLIT; ++k) {
        float4 v = p4[(size_t)k * (512 * 64) + off4];
        s.x += v.x; s.y += v.y; s.z += v.z; s.w += v.w;
    }
    ((float4*)out)[off4] = s;
}

extern "C" void kernel_launch(void* const* d_in, const int* in_sizes, int n_in,
                              void* d_out, int out_size, void* d_ws, size_t ws_size,
                              hipStream_t stream) {
    const float* x = (const float*)d_in[0];
    const float* w = (const float*)d_in[1];
    float* out = (float*)d_out;
    unsigned int* we = (unsigned int*)d_ws;                       // 8.39 MB
    float* part = (float*)((char*)d_ws + (size_t)WE_UINTS * 4);   // 8.39 MB
    (void)ws_size; (void)n_in; (void)in_sizes; (void)out_size;

    pp_expand<<<dim3(256, 2), 256, 0, stream>>>(w, we);
    pp_partial<<<dim3(NSPLIT, 8, 4), 512, 0, stream>>>(x, we, part);
    pp_reduce<<<dim3(256), 128, 0, stream>>>(part, out);   // 256*128 float4 = 131072 floats
}

// Round 7
// 83.582 us; speedup vs baseline: 1.0128x; 1.0128x over previous
//
#include <hip/hip_runtime.h>

// PiecewisePolynomial: out[b,o] = sum_i sum_j L_j(x_in(b,i)) * w[o, i, 3*seg(b,i)+j]
// B=512, IN_F=256, OUT_F=256, SEGMENTS=16, N=4 (nodes -1,-0.5,0.5,1)
//
// R13: R12 (expand fused into partial via per-block self-expansion) with the
// LDS store-stride bug fixed: s-unit stride is 4 uints (16B), R12 wrote
// (h*8+u)*4*4 = 64B stride -> OOB LDS writes + 3/4 of weights unwritten
// -> NaN. Now dst + (h*8+u)*4, matching the unit layout
// ((il*16+opl)*16+s)*4 exactly as R9's global pp_expand produced.
// Architecture unchanged from R12: each block loads its own raw w chunk
// (32o x 16i x 49 f32) with dword loads, packs f32->f16 in registers
// (identical cvt_pkrtz ops => bit-identical weights), ds_writes into the
// 64KB LDS layout the compute loop consumes. Kills the expand dispatch,
// the we round trip (8.4 W + 32 R MB), one kernel-boundary drain, and the
// gload_lds vmcnt(0) barrier stall. Compute/epilogue/reduce = R9 proven.

typedef _Float16 h2 __attribute__((ext_vector_type(2)));

#define INF     256
#define OUTF    256
#define WSTRIDE 49
#define OSTRIDE (INF * WSTRIDE)       // 12544
#define NSPLIT  16
#define IPB     16

__global__ __launch_bounds__(512, 4)
void pp_partial(const float* __restrict__ x, const float* __restrict__ w,
                float* __restrict__ part) {
    __shared__ unsigned int smem[16384];  // 16i x 16op x 16s x 16B = 64 KB

    const int tid  = threadIdx.x;
    const int wave = tid >> 6, lane = tid & 63;
    const int osub = wave & 3;                 // o-subrange within the 32-o tile
    const int bsub = wave >> 2;                // b-half within the 128-b tile
    const int isplit  = blockIdx.x;            // 0..15
    const int i_base  = isplit * IPB;          // *16
    const int o_base  = blockIdx.y * 32;
    const int b_base  = blockIdx.z * 128;
    const int b = b_base + bsub * 64 + lane;   // this lane's batch row

    // ---- issue x loads first (basis inputs) ----
    const float4* xp = (const float4*)(x + (size_t)b * INF + i_base);
    float4 x0 = xp[0], x1 = xp[1], x2 = xp[2], x3 = xp[3];

    // ---- in-block expand: thread t owns w row (o_loc = t>>4, il = t&15).
    // Two half-rows of 25 dwords each; pack 8 s-units per half.
    // smem unit (il, opl, s) at uint offset ((il*16+opl)*16+s)*4;
    // e = o_loc&1 selects uints {0,1} / {2,3} within the unit (8B, aligned).
    {
        const int o_loc = tid >> 4;            // 0..31
        const int il    = tid & 15;            // 0..15
        const int opl   = o_loc >> 1;
        const int e     = o_loc & 1;
        const float* row = w + (size_t)(o_base + o_loc) * OSTRIDE
                             + (size_t)(i_base + il) * WSTRIDE;
        unsigned int* dst = &smem[((il * 16 + opl) * 16) * 4 + e * 2];

        #pragma unroll
        for (int h = 0; h < 2; ++h) {
            const float* rp = row + 24 * h;
            float f[25];
            #pragma unroll
            for (int k = 0; k < 25; ++k) f[k] = rp[k];
            #pragma unroll
            for (int u = 0; u < 8; ++u) {      // s = h*8 + u
                auto p0 = __builtin_amdgcn_cvt_pkrtz(f[3*u],   f[3*u+1]);
                auto p1 = __builtin_amdgcn_cvt_pkrtz(f[3*u+2], f[3*u+3]);
                uint2 v;
                v.x = __builtin_bit_cast(unsigned int, p0);
                v.y = __builtin_bit_cast(unsigned int, p1);
                *(uint2*)(dst + (h * 8 + u) * 4) = v;   // s-stride: 4 uints = 16B
            }
        }
    }

    // ---- per-lane basis + segment ----
    int sseg[IPB]; h2 cA[IPB], cB[IPB];
    {
        float xs[16] = {x0.x, x0.y, x0.z, x0.w, x1.x, x1.y, x1.z, x1.w,
                        x2.x, x2.y, x2.z, x2.w, x3.x, x3.y, x3.z, x3.w};
        #pragma unroll
        for (int i = 0; i < IPB; ++i) {
            float xx = xs[i];
            int id = (int)((xx + 1.0f) * 8.0f);
            id = id < 0 ? 0 : (id > 15 ? 15 : id);
            float u = (xx - ((float)id * 0.125f - 1.0f)) * 16.0f - 1.0f;
            float a = u + 1.0f, b2 = u + 0.5f, cc = u - 0.5f, d = u - 1.0f;
            float c0 = b2 * cc * d  * (-2.0f / 3.0f);
            float c1 = a  * cc * d  * ( 4.0f / 3.0f);
            float c2 = a  * b2 * d  * (-4.0f / 3.0f);
            float c3 = a  * b2 * cc * ( 2.0f / 3.0f);
            h2 pA; pA[0] = (_Float16)c0; pA[1] = (_Float16)c1;
            h2 pB; pB[0] = (_Float16)c2; pB[1] = (_Float16)c3;
            cA[i] = pA; cB[i] = pB; sseg[i] = id;
        }
    }

    __syncthreads();    // all packs' ds_writes visible; no gload_lds drain

    // ---- uninterrupted compute: 64 ds_read_b128 + 256 fdot2 per lane ----
    // wave covers o = o_base + osub*8 .. +7  (op = osub*4 + pq)
    float acc[8];
    #pragma unroll
    for (int q = 0; q < 8; ++q) acc[q] = 0.0f;

    #pragma unroll
    for (int i = 0; i < IPB; ++i) {
        const unsigned int* p = &smem[(i * 16 + osub * 4) * 64 + sseg[i] * 4];
        #pragma unroll
        for (int pq = 0; pq < 4; ++pq) {
            uint4 v = *(const uint4*)(p + pq * 64);
            acc[2*pq]   = __builtin_amdgcn_fdot2(__builtin_bit_cast(h2, v.x), cA[i],
                                                 acc[2*pq],   false);
            acc[2*pq]   = __builtin_amdgcn_fdot2(__builtin_bit_cast(h2, v.y), cB[i],
                                                 acc[2*pq],   false);
            acc[2*pq+1] = __builtin_amdgcn_fdot2(__builtin_bit_cast(h2, v.z), cA[i],
                                                 acc[2*pq+1], false);
            acc[2*pq+1] = __builtin_amdgcn_fdot2(__builtin_bit_cast(h2, v.w), cB[i],
                                                 acc[2*pq+1], false);
        }
    }

    // ---- LDS transpose (lane=b -> lane=o) + coalesced float4 partial stores ----
    __syncthreads();                      // weights no longer needed
    float* smf = (float*)smem;            // [128 b][33] fp32 = 16.9 KB
    const int b_l0 = bsub * 64 + lane;
    #pragma unroll
    for (int q = 0; q < 8; ++q)
        smf[b_l0 * 33 + osub * 8 + q] = acc[q];
    __syncthreads();

    const int qo = tid & 7;               // o-quad 0..7 (4 floats each)
    const int g  = tid >> 3;              // 0..63
    #pragma unroll
    for (int r = 0; r < 2; ++r) {
        int b_l = g + 64 * r;
        float4 v;
        v.x = smf[b_l * 33 + qo * 4 + 0];
        v.y = smf[b_l * 33 + qo * 4 + 1];
        v.z = smf[b_l * 33 + qo * 4 + 2];
        v.w = smf[b_l * 33 + qo * 4 + 3];
        *(float4*)(part + (size_t)isplit * (512 * 256)
                        + (size_t)(b_base + b_l) * 256 + o_base + qo * 4) = v;
    }
}

__global__ __launch_bounds__(128)
void pp_reduce(const float* __restrict__ part, float* __restrict__ out) {
    const size_t off4 = (size_t)blockIdx.x * 128 + threadIdx.x;  // float4 index
    const float4* p4 = (const float4*)part;
    float4 s = make_float4(0.f, 0.f, 0.f, 0.f);
    #pragma unroll
    for (int k = 0; k < NSPLIT; ++k) {
        float4 v = p4[(size_t)k * (512 * 64) + off4];
        s.x += v.x; s.y += v.y; s.z += v.z; s.w += v.w;
    }
    ((float4*)out)[off4] = s;
}

extern "C" void kernel_launch(void* const* d_in, const int* in_sizes, int n_in,
                              void* d_out, int out_size, void* d_ws, size_t ws_size,
                              hipStream_t stream) {
    const float* x = (const float*)d_in[0];
    const float* w = (const float*)d_in[1];
    float* out = (float*)d_out;
    float* part = (float*)d_ws;                                   // 8.39 MB
    (void)ws_size; (void)n_in; (void)in_sizes; (void)out_size;

    pp_partial<<<dim3(NSPLIT, 8, 4), 512, 0, stream>>>(x, w, part);
    pp_reduce<<<dim3(256), 128, 0, stream>>>(part, out);   // 256*128 float4 = 131072 floats
}

// Round 8
// 80.297 us; speedup vs baseline: 1.0543x; 1.0409x over previous
//
#include <hip/hip_runtime.h>

// PiecewisePolynomial: out[b,o] = sum_i sum_j L_j(x_in(b,i)) * w[o, i, 3*seg(b,i)+j]
// B=512, IN_F=256, OUT_F=256, SEGMENTS=16, N=4 (nodes -1,-0.5,0.5,1)
//
// R14: R13 (fused per-block expand) + two instruction-level fixes found by
// bank/transaction audit:
// (a) LDS write swizzle: R13's pack wrote (il,opl,s,e) at byte
//     il*4096+opl*256+s*16+e*8 -> il,opl vanish mod 128B -> ALL 64 lanes in
//     banks {0..3}: 32-way conflict on every ds_write_b64 (~11x serialize).
//     Now s-slot is XOR-swizzled by il&7 -> 16 bank-slots, ~4-way (~free).
//     Reader folds the XOR into sseg[i] = id ^ (i&7) (same il/op across
//     lanes per instr => uniform XOR, read pattern unchanged).
// (b) w loads as 6x dwordx4 (align-4 memcpy) + 1 dword per 25-dword half
//     (14 VMEM instr/thread vs 50) -> ~4x fewer L1/L2 transactions on the
//     lane-stride-196B pattern.
// Everything else (basis, compute loop, epilogue, part, reduce) = R13.

typedef _Float16 h2 __attribute__((ext_vector_type(2)));
typedef float f4a __attribute__((ext_vector_type(4)));

#define INF     256
#define OUTF    256
#define WSTRIDE 49
#define OSTRIDE (INF * WSTRIDE)       // 12544
#define NSPLIT  16
#define IPB     16

__global__ __launch_bounds__(512, 4)
void pp_partial(const float* __restrict__ x, const float* __restrict__ w,
                float* __restrict__ part) {
    __shared__ unsigned int smem[16384];  // 16i x 16op x 16s x 16B = 64 KB

    const int tid  = threadIdx.x;
    const int wave = tid >> 6, lane = tid & 63;
    const int osub = wave & 3;                 // o-subrange within the 32-o tile
    const int bsub = wave >> 2;                // b-half within the 128-b tile
    const int isplit  = blockIdx.x;            // 0..15
    const int i_base  = isplit * IPB;          // *16
    const int o_base  = blockIdx.y * 32;
    const int b_base  = blockIdx.z * 128;
    const int b = b_base + bsub * 64 + lane;   // this lane's batch row

    // ---- issue x loads first (basis inputs) ----
    const float4* xp = (const float4*)(x + (size_t)b * INF + i_base);
    float4 x0 = xp[0], x1 = xp[1], x2 = xp[2], x3 = xp[3];

    // ---- in-block expand: thread t owns w row (o_loc = t>>4, il = t&15).
    // Two half-rows (dwords 24h .. 24h+24); pack 8 s-units per half.
    // Unit (il,opl,s) stored at s-slot (s ^ (il&7)) -> write banks spread
    // ((s^il)&7)*4 + e*2 : ~4-way instead of 32-way.
    {
        const int o_loc = tid >> 4;            // 0..31
        const int il    = tid & 15;            // 0..15
        const int opl   = o_loc >> 1;
        const int e     = o_loc & 1;
        const int swz   = il & 7;
        const float* row = w + (size_t)(o_base + o_loc) * OSTRIDE
                             + (size_t)(i_base + il) * WSTRIDE;
        unsigned int* dstbase = &smem[(il * 16 + opl) * 64 + e * 2];

        #pragma unroll
        for (int h = 0; h < 2; ++h) {
            const float* rp = row + 24 * h;
            float f[25];
            // 6 x dwordx4 (4B-aligned) + 1 dword = dwords 0..24 of this half
            #pragma unroll
            for (int k = 0; k < 6; ++k) {
                f4a v4;
                __builtin_memcpy(&v4, rp + 4 * k, 16);
                f[4*k+0] = v4.x; f[4*k+1] = v4.y; f[4*k+2] = v4.z; f[4*k+3] = v4.w;
            }
            f[24] = rp[24];
            #pragma unroll
            for (int u = 0; u < 8; ++u) {      // s = h*8 + u
                auto p0 = __builtin_amdgcn_cvt_pkrtz(f[3*u],   f[3*u+1]);
                auto p1 = __builtin_amdgcn_cvt_pkrtz(f[3*u+2], f[3*u+3]);
                uint2 v;
                v.x = __builtin_bit_cast(unsigned int, p0);
                v.y = __builtin_bit_cast(unsigned int, p1);
                *(uint2*)(dstbase + (((h * 8 + u) ^ swz) * 4)) = v;
            }
        }
    }

    // ---- per-lane basis + segment (sseg stores the PRE-SWIZZLED slot) ----
    int sseg[IPB]; h2 cA[IPB], cB[IPB];
    {
        float xs[16] = {x0.x, x0.y, x0.z, x0.w, x1.x, x1.y, x1.z, x1.w,
                        x2.x, x2.y, x2.z, x2.w, x3.x, x3.y, x3.z, x3.w};
        #pragma unroll
        for (int i = 0; i < IPB; ++i) {
            float xx = xs[i];
            int id = (int)((xx + 1.0f) * 8.0f);
            id = id < 0 ? 0 : (id > 15 ? 15 : id);
            float u = (xx - ((float)id * 0.125f - 1.0f)) * 16.0f - 1.0f;
            float a = u + 1.0f, b2 = u + 0.5f, cc = u - 0.5f, d = u - 1.0f;
            float c0 = b2 * cc * d  * (-2.0f / 3.0f);
            float c1 = a  * cc * d  * ( 4.0f / 3.0f);
            float c2 = a  * b2 * d  * (-4.0f / 3.0f);
            float c3 = a  * b2 * cc * ( 2.0f / 3.0f);
            h2 pA; pA[0] = (_Float16)c0; pA[1] = (_Float16)c1;
            h2 pB; pB[0] = (_Float16)c2; pB[1] = (_Float16)c3;
            cA[i] = pA; cB[i] = pB;
            sseg[i] = id ^ (i & 7);            // fold write-side swizzle
        }
    }

    __syncthreads();    // all packs' ds_writes visible

    // ---- uninterrupted compute: 64 ds_read_b128 + 256 fdot2 per lane ----
    // wave covers o = o_base + osub*8 .. +7  (op = osub*4 + pq)
    float acc[8];
    #pragma unroll
    for (int q = 0; q < 8; ++q) acc[q] = 0.0f;

    #pragma unroll
    for (int i = 0; i < IPB; ++i) {
        const unsigned int* p = &smem[(i * 16 + osub * 4) * 64 + sseg[i] * 4];
        #pragma unroll
        for (int pq = 0; pq < 4; ++pq) {
            uint4 v = *(const uint4*)(p + pq * 64);
            acc[2*pq]   = __builtin_amdgcn_fdot2(__builtin_bit_cast(h2, v.x), cA[i],
                                                 acc[2*pq],   false);
            acc[2*pq]   = __builtin_amdgcn_fdot2(__builtin_bit_cast(h2, v.y), cB[i],
                                                 acc[2*pq],   false);
            acc[2*pq+1] = __builtin_amdgcn_fdot2(__builtin_bit_cast(h2, v.z), cA[i],
                                                 acc[2*pq+1], false);
            acc[2*pq+1] = __builtin_amdgcn_fdot2(__builtin_bit_cast(h2, v.w), cB[i],
                                                 acc[2*pq+1], false);
        }
    }

    // ---- LDS transpose (lane=b -> lane=o) + coalesced float4 partial stores ----
    __syncthreads();                      // weights no longer needed
    float* smf = (float*)smem;            // [128 b][33] fp32 = 16.9 KB
    const int b_l0 = bsub * 64 + lane;
    #pragma unroll
    for (int q = 0; q < 8; ++q)
        smf[b_l0 * 33 + osub * 8 + q] = acc[q];
    __syncthreads();

    const int qo = tid & 7;               // o-quad 0..7 (4 floats each)
    const int g  = tid >> 3;              // 0..63
    #pragma unroll
    for (int r = 0; r < 2; ++r) {
        int b_l = g + 64 * r;
        float4 v;
        v.x = smf[b_l * 33 + qo * 4 + 0];
        v.y = smf[b_l * 33 + qo * 4 + 1];
        v.z = smf[b_l * 33 + qo * 4 + 2];
        v.w = smf[b_l * 33 + qo * 4 + 3];
        *(float4*)(part + (size_t)isplit * (512 * 256)
                        + (size_t)(b_base + b_l) * 256 + o_base + qo * 4) = v;
    }
}

__global__ __launch_bounds__(128)
void pp_reduce(const float* __restrict__ part, float* __restrict__ out) {
    const size_t off4 = (size_t)blockIdx.x * 128 + threadIdx.x;  // float4 index
    const float4* p4 = (const float4*)part;
    float4 s = make_float4(0.f, 0.f, 0.f, 0.f);
    #pragma unroll
    for (int k = 0; k < NSPLIT; ++k) {
        float4 v = p4[(size_t)k * (512 * 64) + off4];
        s.x += v.x; s.y += v.y; s.z += v.z; s.w += v.w;
    }
    ((float4*)out)[off4] = s;
}

extern "C" void kernel_launch(void* const* d_in, const int* in_sizes, int n_in,
                              void* d_out, int out_size, void* d_ws, size_t ws_size,
                              hipStream_t stream) {
    const float* x = (const float*)d_in[0];
    const float* w = (const float*)d_in[1];
    float* out = (float*)d_out;
    float* part = (float*)d_ws;                                   // 8.39 MB
    (void)ws_size; (void)n_in; (void)in_sizes; (void)out_size;

    pp_partial<<<dim3(NSPLIT, 8, 4), 512, 0, stream>>>(x, w, part);
    pp_reduce<<<dim3(256), 128, 0, stream>>>(part, out);   // 256*128 float4 = 131072 floats
}